// Round 12
// baseline (1029.396 us; speedup 1.0000x reference)
//
#include <hip/hip_runtime.h>
#include <hip/hip_bf16.h>

#define DCOND 48
#define KBINS 24
#define HID 128
#define TSTEPS 10
#define NPAR 73          // 3*K + 1
#define TAILF 15.0f

typedef __attribute__((ext_vector_type(8))) short v8s;   // 8 bf16 = one MFMA frag
typedef __attribute__((ext_vector_type(4))) float f32x4;
typedef __attribute__((ext_vector_type(4))) unsigned u32x4;

__device__ __forceinline__ short f2bf(float f) {
    __hip_bfloat16 h = __float2bfloat16(f);              // RNE (prep kernel only)
    return __builtin_bit_cast(short, h);
}
__device__ __forceinline__ float bf2f(short s) {
    unsigned u = ((unsigned)(unsigned short)s) << 16;
    return __builtin_bit_cast(float, u);
}
__device__ __forceinline__ float silu_f(float v) {
    return __fdividef(v, 1.0f + __expf(-v));
}

// HW packed fp32->2xbf16 (RNE).
__device__ __forceinline__ unsigned cvt_pk(float a, float b) {
    unsigned r;
    asm("v_cvt_pk_bf16_f32 %0, %1, %2" : "=v"(r) : "v"(a), "v"(b));
    return r;   // low16 = bf16(a), high16 = bf16(b)
}

// 8 fp32 -> bf16 hi-frag + bf16 lo-frag (hi RNE, lo = RNE(x - hi)).
__device__ __forceinline__ void split8(f32x4 a0, f32x4 a1, v8s& hi, v8s& lo) {
    unsigned h0 = cvt_pk(a0[0], a0[1]);
    unsigned h1 = cvt_pk(a0[2], a0[3]);
    unsigned h2 = cvt_pk(a1[0], a1[1]);
    unsigned h3 = cvt_pk(a1[2], a1[3]);
    float l0 = a0[0] - __builtin_bit_cast(float, h0 << 16);
    float l1 = a0[1] - __builtin_bit_cast(float, h0 & 0xffff0000u);
    float l2 = a0[2] - __builtin_bit_cast(float, h1 << 16);
    float l3 = a0[3] - __builtin_bit_cast(float, h1 & 0xffff0000u);
    float l4 = a1[0] - __builtin_bit_cast(float, h2 << 16);
    float l5 = a1[1] - __builtin_bit_cast(float, h2 & 0xffff0000u);
    float l6 = a1[2] - __builtin_bit_cast(float, h3 << 16);
    float l7 = a1[3] - __builtin_bit_cast(float, h3 & 0xffff0000u);
    unsigned q0 = cvt_pk(l0, l1);
    unsigned q1 = cvt_pk(l2, l3);
    unsigned q2 = cvt_pk(l4, l5);
    unsigned q3 = cvt_pk(l6, l7);
    hi = __builtin_bit_cast(v8s, (u32x4){h0, h1, h2, h3});
    lo = __builtin_bit_cast(v8s, (u32x4){q0, q1, q2, q3});
}

// ===========================================================================
// Weight prep (VERBATIM round-10/11, verified): kc-piece-major hi/lo layout.
// Per step (shorts, stride 102400):
//   L0 @0     KC=2 NT=8  piece=8192  | L1 @16384 KC=4 NT=8  piece=8192
//   L2 @49152 KC=4 NT=8  piece=8192  | L3 @81920 KC=4 NT=5  piece=5120
// Piece kc = [hi plane: NT*512 | lo plane: NT*512]. Elem e in plane:
//   nt=e>>9, ln=(e>>3)&63, j=e&7; k=kc*32+(ln>>4)*8+j; n=nt*16+(ln&15).
// ===========================================================================
__global__ void prep_w(const float* __restrict__ W0, const float* __restrict__ W1,
                       const float* __restrict__ W2, const float* __restrict__ W3,
                       short* __restrict__ ws)
{
    int g = blockIdx.x * 256 + threadIdx.x;
    if (g >= TSTEPS * 102400) return;
    int t = g / 102400;
    int o = g % 102400;

    int base, NT, Kreal, Nreal, Nstr;
    const float* W;
    if (o < 16384)      { base = 0;     NT = 8; Kreal = 48;  Nreal = 128; Nstr = 128;  W = W0 + (size_t)t * DCOND * HID; }
    else if (o < 49152) { base = 16384; NT = 8; Kreal = 128; Nreal = 128; Nstr = 128;  W = W1 + (size_t)t * HID * HID; }
    else if (o < 81920) { base = 49152; NT = 8; Kreal = 128; Nreal = 128; Nstr = 128;  W = W2 + (size_t)t * HID * HID; }
    else                { base = 81920; NT = 5; Kreal = 128; Nreal = 73;  Nstr = NPAR; W = W3 + (size_t)t * HID * NPAR; }

    int r     = o - base;
    int psz   = 2 * NT * 512;
    int kc    = r / psz;
    int rem   = r % psz;
    int plane = rem / (NT * 512);
    int e     = rem % (NT * 512);
    int nt = e >> 9;
    int ln = (e >> 3) & 63;
    int j  = e & 7;
    int k  = kc * 32 + (ln >> 4) * 8 + j;
    int n  = nt * 16 + (ln & 15);

    float v = 0.0f;
    if (k < Kreal && n < Nreal) v = W[(size_t)k * Nstr + n];
    short hi = f2bf(v);
    ws[(size_t)t * 102400 + o] = plane ? f2bf(v - bf2f(hi)) : hi;
}

// ===========================================================================
// Main fused kernel — 80-KB blocks WITH round-5 barrier economy:
//   384 threads = 6 waves; wave owns 16 rows x all 128 cols (H wave-private,
//   barriers exist ONLY for the W ping-pong). W streamed as 14 full kc-pieces
//   (hi+lo, 16/10 KB) through 2x16 KB buffers: stage piece i+1 while doing
//   piece i's 24 MFMA/thread. 14 barriers/step. 2 blocks/CU (independent
//   sync domains) fill each other's issue holes.
// ===========================================================================
#define MBLK 96
#define NTHR 384

template<int SHORTS>
__device__ __forceinline__ void stage_piece(const short* __restrict__ g,
                                            short* lds, int tid)
{
    constexpr int R = (SHORTS + 3071) / 3072;   // 384 thr x 8 shorts per round
    const int wuni = (tid >> 6) << 9;           // wave * 512 shorts
    #pragma unroll
    for (int i = 0; i < R; ++i) {
        const int so = i * 3072 + tid * 8;
        if ((SHORTS % 3072 == 0) || so < SHORTS)
            __builtin_amdgcn_global_load_lds(
                (const __attribute__((address_space(1))) void*)(g + so),
                (__attribute__((address_space(3))) void*)(lds + i * 3072 + wuni),
                16, 0, 0);
    }
}

__global__ __launch_bounds__(NTHR, 3)   // 3 waves/EU = 12 waves/CU = 2 blocks/CU
void nsf_mfma(const float* __restrict__ z_g, const float* __restrict__ ctx_g,
              const float* __restrict__ b0g, const float* __restrict__ b1g,
              const float* __restrict__ b2g, const float* __restrict__ b3g,
              const float* __restrict__ locp, const float* __restrict__ sclp,
              const short* __restrict__ wsW, float* __restrict__ out, int B)
{
    __shared__ float Hlds[MBLK * 128];   // 48 KB, rows 512 B, swz (row&7)<<4
    __shared__ short Wbuf[2][8192];      // 2 x 16 KB piece ping-pong
    const int tid  = threadIdx.x;
    const int lane = tid & 63, wave = tid >> 6;   // wave 0..5
    const int blk  = blockIdx.x;

    stage_piece<8192>(wsW, Wbuf[0], tid);        // t=0, L0 piece0 in flight

    // ---- ctx A-frags (round-5 verbatim): split ONCE into persistent regs.
    v8s cxh[2], cxl[2];
    {
        const int arw = wave * 16 + (lane & 15);
        int gidr = blk * MBLK + arw;
        if (gidr > B - 1) gidr = B - 1;
        const int k0 = (lane >> 4) * 8;
        const float* cg = ctx_g + (size_t)gidr * DCOND;
        f32x4 c0 = *(const f32x4*)(cg + k0);
        f32x4 c1 = *(const f32x4*)(cg + k0 + 4);
        split8(c0, c1, cxh[0], cxl[0]);
        if ((lane >> 4) < 2) {                       // k = 32+k0..39+k0 (<48)
            f32x4 c2 = *(const f32x4*)(cg + 32 + k0);
            f32x4 c3 = *(const f32x4*)(cg + 36 + k0);
            split8(c2, c3, cxh[1], cxl[1]);
        } else {                                     // k >= 48: zero pad
            #pragma unroll
            for (int u = 0; u < 8; ++u) { cxh[1][u] = 0; cxl[1][u] = 0; }
        }
    }

    float x = 0.0f, ld = 0.0f;
    if (lane < 16) {
        int gid = blk * MBLK + wave * 16 + lane;
        if (gid > B - 1) gid = B - 1;
        x = z_g[gid];
    }

    const int arow  = wave * 16 + (lane & 15);
    const int asw   = (arow & 7) << 4;
    const int kgH   = (lane >> 4) * 32;    // fp32 8-elem k-group byte offset
    const int ncol  = lane & 15;
    const int crow0 = wave * 16 + (lane >> 4) * 4;

    v8s ah[4], al[4];
    f32x4 acc[8];
    int cur = 0;

    __syncthreads();                       // L0 piece0 visible

#define STAGE(PTR, SZ) stage_piece<SZ>((PTR), Wbuf[cur ^ 1], tid)
#define PIECE8(AH, AL) { const short* bb_ = Wbuf[cur] + lane * 8;                 \
    _Pragma("unroll") for (int n_ = 0; n_ < 8; ++n_) {                            \
      v8s bh_ = *(const v8s*)(bb_ + n_ * 512);                                    \
      v8s bl_ = *(const v8s*)(bb_ + 4096 + n_ * 512);                             \
      acc[n_] = __builtin_amdgcn_mfma_f32_16x16x32_bf16((AH), bh_, acc[n_],0,0,0);\
      acc[n_] = __builtin_amdgcn_mfma_f32_16x16x32_bf16((AL), bh_, acc[n_],0,0,0);\
      acc[n_] = __builtin_amdgcn_mfma_f32_16x16x32_bf16((AH), bl_, acc[n_],0,0,0);} }
#define PIECE5(AH, AL) { const short* bb_ = Wbuf[cur] + lane * 8;                 \
    _Pragma("unroll") for (int n_ = 0; n_ < 5; ++n_) {                            \
      v8s bh_ = *(const v8s*)(bb_ + n_ * 512);                                    \
      v8s bl_ = *(const v8s*)(bb_ + 2560 + n_ * 512);                             \
      acc[n_] = __builtin_amdgcn_mfma_f32_16x16x32_bf16((AH), bh_, acc[n_],0,0,0);\
      acc[n_] = __builtin_amdgcn_mfma_f32_16x16x32_bf16((AL), bh_, acc[n_],0,0,0);\
      acc[n_] = __builtin_amdgcn_mfma_f32_16x16x32_bf16((AH), bl_, acc[n_],0,0,0);} }
#define INITACC(BIAS, NREAL, NW)                                                  \
    _Pragma("unroll") for (int i_ = 0; i_ < (NW); ++i_) {                         \
      const int n_ = i_ * 16 + ncol;                                              \
      const float bv_ = (n_ < (NREAL)) ? (BIAS)[n_] : 0.0f;                       \
      acc[i_] = (f32x4){bv_, bv_, bv_, bv_}; }
#define CW(ACT, NW)                                                               \
    _Pragma("unroll") for (int i_ = 0; i_ < (NW); ++i_) {                         \
      const int n_ = i_ * 16 + ncol;                                              \
      _Pragma("unroll") for (int r_ = 0; r_ < 4; ++r_) {                          \
        const int row_ = crow0 + r_; const int sw_ = (row_ & 7) << 4;             \
        float v_ = acc[i_][r_]; if (ACT) v_ = silu_f(v_);                         \
        *(float*)((char*)Hlds + row_ * 512 + ((n_ * 4) ^ sw_)) = v_; } }
#define ASPLIT { const char* hr_ = (const char*)Hlds + arow * 512;                \
    _Pragma("unroll") for (int kc_ = 0; kc_ < 4; ++kc_) {                         \
      const int kb_ = kc_ * 128 + kgH;                                            \
      f32x4 a0_ = *(const f32x4*)(hr_ + (kb_ ^ asw));                             \
      f32x4 a1_ = *(const f32x4*)(hr_ + ((kb_ + 16) ^ asw));                      \
      split8(a0_, a1_, ah[kc_], al[kc_]); } }
#define BAR __syncthreads(); cur ^= 1

    #pragma unroll 1
    for (int t = 0; t < TSTEPS; ++t) {
        const short* ws0 = wsW + (size_t)t * 102400;
        const short* wsn = wsW + (size_t)((t + 1) % TSTEPS) * 102400;

        // ---- L0 (A from ctx regs; 2 pieces)
        INITACC(b0g + t * HID, HID, 8);
        STAGE(ws0 +  8192, 8192); PIECE8(cxh[0], cxl[0]);          BAR;
        STAGE(ws0 + 16384, 8192); PIECE8(cxh[1], cxl[1]); CW(true, 8); BAR;

        // ---- L1 (4 pieces)
        STAGE(ws0 + 24576, 8192); ASPLIT; INITACC(b1g + t * HID, HID, 8);
                                  PIECE8(ah[0], al[0]);            BAR;
        STAGE(ws0 + 32768, 8192); PIECE8(ah[1], al[1]);            BAR;
        STAGE(ws0 + 40960, 8192); PIECE8(ah[2], al[2]);            BAR;
        STAGE(ws0 + 49152, 8192); PIECE8(ah[3], al[3]); CW(true, 8); BAR;

        // ---- L2 (4 pieces)
        STAGE(ws0 + 57344, 8192); ASPLIT; INITACC(b2g + t * HID, HID, 8);
                                  PIECE8(ah[0], al[0]);            BAR;
        STAGE(ws0 + 65536, 8192); PIECE8(ah[1], al[1]);            BAR;
        STAGE(ws0 + 73728, 8192); PIECE8(ah[2], al[2]);            BAR;
        STAGE(ws0 + 81920, 5120); PIECE8(ah[3], al[3]); CW(true, 8); BAR;

        // ---- L3 (4 pieces, NT=5)
        STAGE(ws0 + 87040, 5120); ASPLIT; INITACC(b3g + t * NPAR, NPAR, 5);
                                  PIECE5(ah[0], al[0]);            BAR;
        STAGE(ws0 + 92160, 5120); PIECE5(ah[1], al[1]);            BAR;
        STAGE(ws0 + 97280, 5120); PIECE5(ah[2], al[2]);            BAR;
        STAGE(wsn,         8192); PIECE5(ah[3], al[3]); CW(false, 5); BAR;

        // ---- spline: lane<16, own wave's row (H wave-private; next H-write
        // is CW(L0,t+1) which sits after 2 barriers this wave must also pass).
        if (lane < 16) {
            const int srow = wave * 16 + lane;
            const char* hrow = (const char*)Hlds + srow * 512;
            const int sw = (srow & 7) << 4;

            float pw[KBINS], ph[KBINS];
            #pragma unroll
            for (int g = 0; g < 6; ++g) {
                f32x4 vw = *(const f32x4*)(hrow + ((g * 16) ^ sw));
                f32x4 vh = *(const f32x4*)(hrow + (((g + 6) * 16) ^ sw));
                #pragma unroll
                for (int u = 0; u < 4; ++u) { pw[g * 4 + u] = vw[u]; ph[g * 4 + u] = vh[u]; }
            }
            float mw = pw[0], mh = ph[0];
            #pragma unroll
            for (int i = 1; i < KBINS; ++i) { mw = fmaxf(mw, pw[i]); mh = fmaxf(mh, ph[i]); }
            float wsum = 0.0f, hsum = 0.0f;
            #pragma unroll
            for (int i = 0; i < KBINS; ++i) {
                pw[i] = __expf(pw[i] - mw); wsum += pw[i];
                ph[i] = __expf(ph[i] - mh); hsum += ph[i];
            }
            const float wmul = __fdividef(2.0f * TAILF, wsum);
            const float hmul = __fdividef(2.0f * TAILF, hsum);

            // reference semantics: cw[0]=-TAIL, cw[i>=1]=RAW cumsum (no shift)
            float cw = 0.0f, ch = 0.0f;
            float cwk = -TAILF, chk = -TAILF;
            float wk = pw[0] * wmul, hk = ph[0] * hmul;
            int idx = 0;
            #pragma unroll
            for (int i = 1; i < KBINS; ++i) {
                cw += pw[i - 1] * wmul;
                ch += ph[i - 1] * hmul;
                if (cw < x) {
                    cwk = cw; chk = ch;
                    wk = pw[i] * wmul; hk = ph[i] * hmul;
                    idx = i;
                }
            }
            float d0 = *(const float*)(hrow + (((2 * KBINS + idx) * 4) ^ sw));
            float d1 = *(const float*)(hrow + (((2 * KBINS + idx + 1) * 4) ^ sw));
            const float dk  = fmaxf(d0, 0.0f) + __logf(1.0f + __expf(-fabsf(d0))) + 0.001f;
            const float dk1 = fmaxf(d1, 0.0f) + __logf(1.0f + __expf(-fabsf(d1))) + 0.001f;

            const bool inside = (x >= -TAILF) && (x <= TAILF);
            const float sr = __fdividef(hk, wk);
            float xi = __fdividef(x - cwk, wk);
            xi = fminf(fmaxf(xi, 1e-6f), 1.0f - 1e-6f);
            const float om  = 1.0f - xi;
            const float xio = xi * om;
            const float numer = hk * (sr * xi * xi + dk * xio);
            const float denom = sr + (dk + dk1 - 2.0f * sr) * xio;
            const float y = chk + __fdividef(numer, denom);
            const float dyd = __fdividef(sr * sr * (dk1 * xi * xi + 2.0f * sr * xio + dk * om * om),
                                         denom * denom);
            // fold 3 logs into 1: log(a)+log(b)-log(c) = log(a*b/c); clamps kept
            const float lg = __logf(__fdividef(fmaxf(dyd, 1e-10f) * fmaxf(hk, 1e-10f),
                                               fmaxf(wk, 1e-10f)));
            x  = inside ? y : x;
            ld += inside ? lg : 0.0f;
        }
    }
#undef STAGE
#undef PIECE8
#undef PIECE5
#undef INITACC
#undef CW
#undef ASPLIT
#undef BAR

    if (lane < 16) {
        const int gid = blk * MBLK + wave * 16 + lane;
        if (gid < B) {
            const float s = fmaxf(sclp[0], 0.1f);
            out[gid]     = fmaf(x, s, locp[0]);
            out[B + gid] = ld;
        }
    }
}

// ===========================================================================
// Fallback (proven round-2 fp32 kernel) if ws is too small for weight prep
// ===========================================================================
#define FBLK 256
template<int KIN, int WS, int NOUT, bool ACT>
__device__ __forceinline__ void dense_chunk(const float* __restrict__ W,
                                            const float* __restrict__ bias,
                                            int j0, const float (&hin)[KIN],
                                            float* __restrict__ sb, int tid)
{
    #pragma unroll 1
    for (int jj = 0; jj < NOUT; jj += 8) {
        const int j = j0 + jj;
        float a[8];
        #pragma unroll
        for (int u = 0; u < 8; ++u) a[u] = bias[j + u];
        #pragma unroll
        for (int k = 0; k < KIN; ++k) {
            const float* w = W + k * WS + j;
            const float hk = hin[k];
            #pragma unroll
            for (int u = 0; u < 8; ++u) a[u] = fmaf(hk, w[u], a[u]);
        }
        #pragma unroll
        for (int u = 0; u < 8; ++u) {
            float v = ACT ? silu_f(a[u]) : a[u];
            sb[(jj + u) * FBLK + tid] = v;
        }
    }
}

__global__ __launch_bounds__(FBLK, 2)
void nsf_fwd_slow(const float* __restrict__ z_g, const float* __restrict__ ctx_g,
                  const float* __restrict__ W0g, const float* __restrict__ b0g,
                  const float* __restrict__ W1g, const float* __restrict__ b1g,
                  const float* __restrict__ W2g, const float* __restrict__ b2g,
                  const float* __restrict__ W3g, const float* __restrict__ b3g,
                  const float* __restrict__ locp, const float* __restrict__ sclp,
                  float* __restrict__ out, int B)
{
    __shared__ float sbuf[64 * FBLK];
    const int tid = threadIdx.x;
    const int gid = blockIdx.x * FBLK + tid;
    if (gid >= B) return;
    float x = z_g[gid], ld = 0.0f;
    #pragma unroll 1
    for (int t = 0; t < TSTEPS; ++t) {
        asm volatile("" ::: "memory");
        const float* W0 = W0g + (size_t)t * DCOND * HID;
        const float* b0 = b0g + (size_t)t * HID;
        const float* W1 = W1g + (size_t)t * HID * HID;
        const float* b1 = b1g + (size_t)t * HID;
        const float* W2 = W2g + (size_t)t * HID * HID;
        const float* b2 = b2g + (size_t)t * HID;
        const float* W3 = W3g + (size_t)t * HID * NPAR;
        const float* b3 = b3g + (size_t)t * NPAR;
        float ctx[DCOND];
        #pragma unroll
        for (int k = 0; k < DCOND; ++k) ctx[k] = ctx_g[(size_t)gid * DCOND + k];
        float h[HID];
        dense_chunk<DCOND, HID, 64, true>(W0, b0, 0, ctx, sbuf, tid);
        #pragma unroll
        for (int j = 0; j < 64; ++j) h[j] = sbuf[j * FBLK + tid];
        dense_chunk<DCOND, HID, 64, true>(W0, b0, 64, ctx, sbuf, tid);
        #pragma unroll
        for (int j = 0; j < 64; ++j) h[64 + j] = sbuf[j * FBLK + tid];
        #pragma unroll 1
        for (int l = 0; l < 2; ++l) {
            const float* W  = (l == 0) ? W1 : W2;
            const float* bb = (l == 0) ? b1 : b2;
            float hlo[64];
            dense_chunk<HID, HID, 64, true>(W, bb, 0, h, sbuf, tid);
            #pragma unroll
            for (int j = 0; j < 64; ++j) hlo[j] = sbuf[j * FBLK + tid];
            dense_chunk<HID, HID, 64, true>(W, bb, 64, h, sbuf, tid);
            #pragma unroll
            for (int j = 0; j < 64; ++j) h[64 + j] = sbuf[j * FBLK + tid];
            #pragma unroll
            for (int j = 0; j < 64; ++j) h[j] = hlo[j];
        }
        float p[NPAR];
        dense_chunk<HID, NPAR, 64, false>(W3, b3, 0, h, sbuf, tid);
        #pragma unroll
        for (int j = 0; j < 64; ++j) p[j] = sbuf[j * FBLK + tid];
        dense_chunk<HID, NPAR, 8, false>(W3, b3, 64, h, sbuf, tid);
        #pragma unroll
        for (int j = 0; j < 8; ++j) p[64 + j] = sbuf[j * FBLK + tid];
        {
            float a = b3[72];
            #pragma unroll
            for (int k = 0; k < HID; ++k) a = fmaf(h[k], W3[k * NPAR + 72], a);
            p[72] = a;
        }
        float mw = p[0];
        #pragma unroll
        for (int i = 1; i < KBINS; ++i) mw = fmaxf(mw, p[i]);
        float we[KBINS]; float wsum = 0.0f;
        #pragma unroll
        for (int i = 0; i < KBINS; ++i) { we[i] = __expf(p[i] - mw); wsum += we[i]; }
        const float wmul = __fdividef(2.0f * TAILF, wsum);
        float mh = p[KBINS];
        #pragma unroll
        for (int i = 1; i < KBINS; ++i) mh = fmaxf(mh, p[KBINS + i]);
        float he[KBINS]; float hsum = 0.0f;
        #pragma unroll
        for (int i = 0; i < KBINS; ++i) { he[i] = __expf(p[KBINS + i] - mh); hsum += he[i]; }
        const float hmul = __fdividef(2.0f * TAILF, hsum);
        float dvv[KBINS + 1];
        #pragma unroll
        for (int i = 0; i <= KBINS; ++i) {
            float xd = p[2 * KBINS + i];
            dvv[i] = fmaxf(xd, 0.0f) + __logf(1.0f + __expf(-fabsf(xd))) + 0.001f;
        }
        float cw = 0.0f, ch = 0.0f, cwk = -TAILF, chk = -TAILF;
        float wk = we[0] * wmul, hk = he[0] * hmul, dk = dvv[0], dk1 = dvv[1];
        #pragma unroll
        for (int i = 1; i < KBINS; ++i) {
            cw += we[i - 1] * wmul;
            ch += he[i - 1] * hmul;
            if (cw < x) {
                cwk = cw; chk = ch;
                wk = we[i] * wmul; hk = he[i] * hmul;
                dk = dvv[i]; dk1 = dvv[i + 1];
            }
        }
        const bool inside = (x >= -TAILF) && (x <= TAILF);
        const float sr = __fdividef(hk, wk);
        float xi = __fdividef(x - cwk, wk);
        xi = fminf(fmaxf(xi, 1e-6f), 1.0f - 1e-6f);
        const float om  = 1.0f - xi;
        const float xio = xi * om;
        const float numer = hk * (sr * xi * xi + dk * xio);
        const float denom = sr + (dk + dk1 - 2.0f * sr) * xio;
        const float y = chk + __fdividef(numer, denom);
        const float dyd = __fdividef(sr * sr * (dk1 * xi * xi + 2.0f * sr * xio + dk * om * om),
                                     denom * denom);
        const float lg = __logf(fmaxf(dyd, 1e-10f)) + __logf(fmaxf(hk, 1e-10f))
                       - __logf(fmaxf(wk, 1e-10f));
        x  = inside ? y : x;
        ld += inside ? lg : 0.0f;
    }
    const float s = fmaxf(sclp[0], 0.1f);
    out[gid]     = fmaf(x, s, locp[0]);
    out[B + gid] = ld;
}

// ===========================================================================
extern "C" void kernel_launch(void* const* d_in, const int* in_sizes, int n_in,
                              void* d_out, int out_size, void* d_ws, size_t ws_size,
                              hipStream_t stream) {
    const float* z    = (const float*)d_in[0];
    const float* ctx  = (const float*)d_in[1];
    const float* W0   = (const float*)d_in[2];
    const float* b0   = (const float*)d_in[3];
    const float* W1   = (const float*)d_in[4];
    const float* b1   = (const float*)d_in[5];
    const float* W2   = (const float*)d_in[6];
    const float* b2   = (const float*)d_in[7];
    const float* W3   = (const float*)d_in[8];
    const float* b3   = (const float*)d_in[9];
    const float* loc  = (const float*)d_in[10];
    const float* scl  = (const float*)d_in[11];
    float* out = (float*)d_out;
    const int B = in_sizes[0];

    const size_t ws_need = (size_t)TSTEPS * 102400 * sizeof(short);   // 2,048,000 B
    if (ws_size < ws_need) {
        const int nblk = (B + FBLK - 1) / FBLK;
        hipLaunchKernelGGL(nsf_fwd_slow, dim3(nblk), dim3(FBLK), 0, stream,
                           z, ctx, W0, b0, W1, b1, W2, b2, W3, b3, loc, scl, out, B);
        return;
    }

    short* ws = (short*)d_ws;
    const int prep_total = TSTEPS * 102400;
    hipLaunchKernelGGL(prep_w, dim3((prep_total + 255) / 256), dim3(256), 0, stream,
                       W0, W1, W2, W3, ws);

    const int nblk = (B + MBLK - 1) / MBLK;   // 1366 blocks
    hipLaunchKernelGGL(nsf_mfma, dim3(nblk), dim3(NTHR), 0, stream,
                       z, ctx, b0, b1, b2, b3, loc, scl, ws, out, B);
}

// Round 13
// 669.023 us; speedup vs baseline: 1.5387x; 1.5387x over previous
//
#include <hip/hip_runtime.h>
#include <hip/hip_bf16.h>

#define DCOND 48
#define KBINS 24
#define HID 128
#define TSTEPS 10
#define NPAR 73          // 3*K + 1
#define TAILF 15.0f

typedef __attribute__((ext_vector_type(8))) short v8s;   // 8 bf16 = one MFMA frag
typedef __attribute__((ext_vector_type(4))) float f32x4;
typedef __attribute__((ext_vector_type(4))) unsigned u32x4;

__device__ __forceinline__ short f2bf(float f) {
    __hip_bfloat16 h = __float2bfloat16(f);              // RNE (prep kernel only)
    return __builtin_bit_cast(short, h);
}
__device__ __forceinline__ float bf2f(short s) {
    unsigned u = ((unsigned)(unsigned short)s) << 16;
    return __builtin_bit_cast(float, u);
}
__device__ __forceinline__ float silu_f(float v) {
    return __fdividef(v, 1.0f + __expf(-v));
}

// HW packed fp32->2xbf16 (RNE).
__device__ __forceinline__ unsigned cvt_pk(float a, float b) {
    unsigned r;
    asm("v_cvt_pk_bf16_f32 %0, %1, %2" : "=v"(r) : "v"(a), "v"(b));
    return r;   // low16 = bf16(a), high16 = bf16(b)
}

// 8 fp32 -> bf16 hi-frag + bf16 lo-frag (hi RNE, lo = RNE(x - hi)).
__device__ __forceinline__ void split8(f32x4 a0, f32x4 a1, v8s& hi, v8s& lo) {
    unsigned h0 = cvt_pk(a0[0], a0[1]);
    unsigned h1 = cvt_pk(a0[2], a0[3]);
    unsigned h2 = cvt_pk(a1[0], a1[1]);
    unsigned h3 = cvt_pk(a1[2], a1[3]);
    float l0 = a0[0] - __builtin_bit_cast(float, h0 << 16);
    float l1 = a0[1] - __builtin_bit_cast(float, h0 & 0xffff0000u);
    float l2 = a0[2] - __builtin_bit_cast(float, h1 << 16);
    float l3 = a0[3] - __builtin_bit_cast(float, h1 & 0xffff0000u);
    float l4 = a1[0] - __builtin_bit_cast(float, h2 << 16);
    float l5 = a1[1] - __builtin_bit_cast(float, h2 & 0xffff0000u);
    float l6 = a1[2] - __builtin_bit_cast(float, h3 << 16);
    float l7 = a1[3] - __builtin_bit_cast(float, h3 & 0xffff0000u);
    unsigned q0 = cvt_pk(l0, l1);
    unsigned q1 = cvt_pk(l2, l3);
    unsigned q2 = cvt_pk(l4, l5);
    unsigned q3 = cvt_pk(l6, l7);
    hi = __builtin_bit_cast(v8s, (u32x4){h0, h1, h2, h3});
    lo = __builtin_bit_cast(v8s, (u32x4){q0, q1, q2, q3});
}

// ===========================================================================
// Weight prep (VERBATIM round-10/11/12, verified): kc-piece-major hi/lo.
// Per step (shorts, stride 102400):
//   L0 @0     KC=2 NT=8  piece=8192  | L1 @16384 KC=4 NT=8  piece=8192
//   L2 @49152 KC=4 NT=8  piece=8192  | L3 @81920 KC=4 NT=5  piece=5120
// Piece kc = [hi plane: NT*512 | lo plane: NT*512]. Elem e in plane:
//   nt=e>>9, ln=(e>>3)&63, j=e&7; k=kc*32+(ln>>4)*8+j; n=nt*16+(ln&15).
// ===========================================================================
__global__ void prep_w(const float* __restrict__ W0, const float* __restrict__ W1,
                       const float* __restrict__ W2, const float* __restrict__ W3,
                       short* __restrict__ ws)
{
    int g = blockIdx.x * 256 + threadIdx.x;
    if (g >= TSTEPS * 102400) return;
    int t = g / 102400;
    int o = g % 102400;

    int base, NT, Kreal, Nreal, Nstr;
    const float* W;
    if (o < 16384)      { base = 0;     NT = 8; Kreal = 48;  Nreal = 128; Nstr = 128;  W = W0 + (size_t)t * DCOND * HID; }
    else if (o < 49152) { base = 16384; NT = 8; Kreal = 128; Nreal = 128; Nstr = 128;  W = W1 + (size_t)t * HID * HID; }
    else if (o < 81920) { base = 49152; NT = 8; Kreal = 128; Nreal = 128; Nstr = 128;  W = W2 + (size_t)t * HID * HID; }
    else                { base = 81920; NT = 5; Kreal = 128; Nreal = 73;  Nstr = NPAR; W = W3 + (size_t)t * HID * NPAR; }

    int r     = o - base;
    int psz   = 2 * NT * 512;
    int kc    = r / psz;
    int rem   = r % psz;
    int plane = rem / (NT * 512);
    int e     = rem % (NT * 512);
    int nt = e >> 9;
    int ln = (e >> 3) & 63;
    int j  = e & 7;
    int k  = kc * 32 + (ln >> 4) * 8 + j;
    int n  = nt * 16 + (ln & 15);

    float v = 0.0f;
    if (k < Kreal && n < Nreal) v = W[(size_t)k * Nstr + n];
    short hi = f2bf(v);
    ws[(size_t)t * 102400 + o] = plane ? f2bf(v - bf2f(hi)) : hi;
}

// ===========================================================================
// Main fused kernel — TWO INDEPENDENT 64-KB DOMAINS PER CU (clean test):
//   256 threads = 4 waves; wave owns 16 rows x all 128 cols (H wave-private;
//   barriers exist ONLY for the W ping-pong). 14 kc-piece barriers/step.
//   2 blocks/CU (94 KB LDS slack -> fit guaranteed), launch_bounds(256,2)
//   (VGPR cap 256 -> no spill). Same 8 waves/CU as round 5, but in two
//   independent barrier domains: block B computes while block A drains.
// ===========================================================================
#define MBLK 64
#define NTHR 256

template<int SHORTS>
__device__ __forceinline__ void stage_piece(const short* __restrict__ g,
                                            short* lds, int tid)
{
    constexpr int R = (SHORTS + 2047) / 2048;   // 256 thr x 8 shorts per round
    const int wuni = (tid >> 6) << 9;           // wave * 512 shorts
    #pragma unroll
    for (int i = 0; i < R; ++i) {
        const int so = i * 2048 + tid * 8;
        if ((SHORTS % 2048 == 0) || so < SHORTS)
            __builtin_amdgcn_global_load_lds(
                (const __attribute__((address_space(1))) void*)(g + so),
                (__attribute__((address_space(3))) void*)(lds + i * 2048 + wuni),
                16, 0, 0);
    }
}

__global__ __launch_bounds__(NTHR, 2)   // 2 waves/EU = 2 blocks/CU, VGPR<=256
void nsf_mfma(const float* __restrict__ z_g, const float* __restrict__ ctx_g,
              const float* __restrict__ b0g, const float* __restrict__ b1g,
              const float* __restrict__ b2g, const float* __restrict__ b3g,
              const float* __restrict__ locp, const float* __restrict__ sclp,
              const short* __restrict__ wsW, float* __restrict__ out, int B)
{
    __shared__ float Hlds[MBLK * 128];   // 32 KB, rows 512 B, swz (row&7)<<4
    __shared__ short Wbuf[2][8192];      // 2 x 16 KB piece ping-pong
    const int tid  = threadIdx.x;
    const int lane = tid & 63, wave = tid >> 6;   // wave 0..3
    const int blk  = blockIdx.x;

    stage_piece<8192>(wsW, Wbuf[0], tid);        // t=0, L0 piece0 in flight

    // ---- ctx A-frags (round-5 verbatim): split ONCE into persistent regs.
    v8s cxh[2], cxl[2];
    {
        const int arw = wave * 16 + (lane & 15);
        int gidr = blk * MBLK + arw;
        if (gidr > B - 1) gidr = B - 1;
        const int k0 = (lane >> 4) * 8;
        const float* cg = ctx_g + (size_t)gidr * DCOND;
        f32x4 c0 = *(const f32x4*)(cg + k0);
        f32x4 c1 = *(const f32x4*)(cg + k0 + 4);
        split8(c0, c1, cxh[0], cxl[0]);
        if ((lane >> 4) < 2) {                       // k = 32+k0..39+k0 (<48)
            f32x4 c2 = *(const f32x4*)(cg + 32 + k0);
            f32x4 c3 = *(const f32x4*)(cg + 36 + k0);
            split8(c2, c3, cxh[1], cxl[1]);
        } else {                                     // k >= 48: zero pad
            #pragma unroll
            for (int u = 0; u < 8; ++u) { cxh[1][u] = 0; cxl[1][u] = 0; }
        }
    }

    float x = 0.0f, ld = 0.0f;
    if (lane < 16) {
        int gid = blk * MBLK + wave * 16 + lane;
        if (gid > B - 1) gid = B - 1;
        x = z_g[gid];
    }

    const int arow  = wave * 16 + (lane & 15);
    const int asw   = (arow & 7) << 4;
    const int kgH   = (lane >> 4) * 32;    // fp32 8-elem k-group byte offset
    const int ncol  = lane & 15;
    const int crow0 = wave * 16 + (lane >> 4) * 4;

    v8s ah[4], al[4];
    f32x4 acc[8];
    int cur = 0;

    __syncthreads();                       // L0 piece0 visible

#define STAGE(PTR, SZ) stage_piece<SZ>((PTR), Wbuf[cur ^ 1], tid)
#define PIECE8(AH, AL) { const short* bb_ = Wbuf[cur] + lane * 8;                 \
    _Pragma("unroll") for (int n_ = 0; n_ < 8; ++n_) {                            \
      v8s bh_ = *(const v8s*)(bb_ + n_ * 512);                                    \
      v8s bl_ = *(const v8s*)(bb_ + 4096 + n_ * 512);                             \
      acc[n_] = __builtin_amdgcn_mfma_f32_16x16x32_bf16((AH), bh_, acc[n_],0,0,0);\
      acc[n_] = __builtin_amdgcn_mfma_f32_16x16x32_bf16((AL), bh_, acc[n_],0,0,0);\
      acc[n_] = __builtin_amdgcn_mfma_f32_16x16x32_bf16((AH), bl_, acc[n_],0,0,0);} }
#define PIECE5(AH, AL) { const short* bb_ = Wbuf[cur] + lane * 8;                 \
    _Pragma("unroll") for (int n_ = 0; n_ < 5; ++n_) {                            \
      v8s bh_ = *(const v8s*)(bb_ + n_ * 512);                                    \
      v8s bl_ = *(const v8s*)(bb_ + 2560 + n_ * 512);                             \
      acc[n_] = __builtin_amdgcn_mfma_f32_16x16x32_bf16((AH), bh_, acc[n_],0,0,0);\
      acc[n_] = __builtin_amdgcn_mfma_f32_16x16x32_bf16((AL), bh_, acc[n_],0,0,0);\
      acc[n_] = __builtin_amdgcn_mfma_f32_16x16x32_bf16((AH), bl_, acc[n_],0,0,0);} }
#define INITACC(BIAS, NREAL, NW)                                                  \
    _Pragma("unroll") for (int i_ = 0; i_ < (NW); ++i_) {                         \
      const int n_ = i_ * 16 + ncol;                                              \
      const float bv_ = (n_ < (NREAL)) ? (BIAS)[n_] : 0.0f;                       \
      acc[i_] = (f32x4){bv_, bv_, bv_, bv_}; }
#define CW(ACT, NW)                                                               \
    _Pragma("unroll") for (int i_ = 0; i_ < (NW); ++i_) {                         \
      const int n_ = i_ * 16 + ncol;                                              \
      _Pragma("unroll") for (int r_ = 0; r_ < 4; ++r_) {                          \
        const int row_ = crow0 + r_; const int sw_ = (row_ & 7) << 4;             \
        float v_ = acc[i_][r_]; if (ACT) v_ = silu_f(v_);                         \
        *(float*)((char*)Hlds + row_ * 512 + ((n_ * 4) ^ sw_)) = v_; } }
#define ASPLIT { const char* hr_ = (const char*)Hlds + arow * 512;                \
    _Pragma("unroll") for (int kc_ = 0; kc_ < 4; ++kc_) {                         \
      const int kb_ = kc_ * 128 + kgH;                                            \
      f32x4 a0_ = *(const f32x4*)(hr_ + (kb_ ^ asw));                             \
      f32x4 a1_ = *(const f32x4*)(hr_ + ((kb_ + 16) ^ asw));                      \
      split8(a0_, a1_, ah[kc_], al[kc_]); } }
#define BAR __syncthreads(); cur ^= 1

    #pragma unroll 1
    for (int t = 0; t < TSTEPS; ++t) {
        const short* ws0 = wsW + (size_t)t * 102400;
        const short* wsn = wsW + (size_t)((t + 1) % TSTEPS) * 102400;

        // ---- L0 (A from ctx regs; 2 pieces)
        INITACC(b0g + t * HID, HID, 8);
        STAGE(ws0 +  8192, 8192); PIECE8(cxh[0], cxl[0]);          BAR;
        STAGE(ws0 + 16384, 8192); PIECE8(cxh[1], cxl[1]); CW(true, 8); BAR;

        // ---- L1 (4 pieces)
        STAGE(ws0 + 24576, 8192); ASPLIT; INITACC(b1g + t * HID, HID, 8);
                                  PIECE8(ah[0], al[0]);            BAR;
        STAGE(ws0 + 32768, 8192); PIECE8(ah[1], al[1]);            BAR;
        STAGE(ws0 + 40960, 8192); PIECE8(ah[2], al[2]);            BAR;
        STAGE(ws0 + 49152, 8192); PIECE8(ah[3], al[3]); CW(true, 8); BAR;

        // ---- L2 (4 pieces)
        STAGE(ws0 + 57344, 8192); ASPLIT; INITACC(b2g + t * HID, HID, 8);
                                  PIECE8(ah[0], al[0]);            BAR;
        STAGE(ws0 + 65536, 8192); PIECE8(ah[1], al[1]);            BAR;
        STAGE(ws0 + 73728, 8192); PIECE8(ah[2], al[2]);            BAR;
        STAGE(ws0 + 81920, 5120); PIECE8(ah[3], al[3]); CW(true, 8); BAR;

        // ---- L3 (4 pieces, NT=5)
        STAGE(ws0 + 87040, 5120); ASPLIT; INITACC(b3g + t * NPAR, NPAR, 5);
                                  PIECE5(ah[0], al[0]);            BAR;
        STAGE(ws0 + 92160, 5120); PIECE5(ah[1], al[1]);            BAR;
        STAGE(ws0 + 97280, 5120); PIECE5(ah[2], al[2]);            BAR;
        STAGE(wsn,         8192); PIECE5(ah[3], al[3]); CW(false, 5); BAR;

        // ---- spline: lane<16, own wave's row (H wave-private; next H-write
        // is CW(L0,t+1) which sits after 2 barriers this wave must also pass).
        if (lane < 16) {
            const int srow = wave * 16 + lane;
            const char* hrow = (const char*)Hlds + srow * 512;
            const int sw = (srow & 7) << 4;

            float pw[KBINS], ph[KBINS];
            #pragma unroll
            for (int g = 0; g < 6; ++g) {
                f32x4 vw = *(const f32x4*)(hrow + ((g * 16) ^ sw));
                f32x4 vh = *(const f32x4*)(hrow + (((g + 6) * 16) ^ sw));
                #pragma unroll
                for (int u = 0; u < 4; ++u) { pw[g * 4 + u] = vw[u]; ph[g * 4 + u] = vh[u]; }
            }
            float mw = pw[0], mh = ph[0];
            #pragma unroll
            for (int i = 1; i < KBINS; ++i) { mw = fmaxf(mw, pw[i]); mh = fmaxf(mh, ph[i]); }
            float wsum = 0.0f, hsum = 0.0f;
            #pragma unroll
            for (int i = 0; i < KBINS; ++i) {
                pw[i] = __expf(pw[i] - mw); wsum += pw[i];
                ph[i] = __expf(ph[i] - mh); hsum += ph[i];
            }
            const float wmul = __fdividef(2.0f * TAILF, wsum);
            const float hmul = __fdividef(2.0f * TAILF, hsum);

            // reference semantics: cw[0]=-TAIL, cw[i>=1]=RAW cumsum (no shift)
            float cw = 0.0f, ch = 0.0f;
            float cwk = -TAILF, chk = -TAILF;
            float wk = pw[0] * wmul, hk = ph[0] * hmul;
            int idx = 0;
            #pragma unroll
            for (int i = 1; i < KBINS; ++i) {
                cw += pw[i - 1] * wmul;
                ch += ph[i - 1] * hmul;
                if (cw < x) {
                    cwk = cw; chk = ch;
                    wk = pw[i] * wmul; hk = ph[i] * hmul;
                    idx = i;
                }
            }
            float d0 = *(const float*)(hrow + (((2 * KBINS + idx) * 4) ^ sw));
            float d1 = *(const float*)(hrow + (((2 * KBINS + idx + 1) * 4) ^ sw));
            const float dk  = fmaxf(d0, 0.0f) + __logf(1.0f + __expf(-fabsf(d0))) + 0.001f;
            const float dk1 = fmaxf(d1, 0.0f) + __logf(1.0f + __expf(-fabsf(d1))) + 0.001f;

            const bool inside = (x >= -TAILF) && (x <= TAILF);
            const float sr = __fdividef(hk, wk);
            float xi = __fdividef(x - cwk, wk);
            xi = fminf(fmaxf(xi, 1e-6f), 1.0f - 1e-6f);
            const float om  = 1.0f - xi;
            const float xio = xi * om;
            const float numer = hk * (sr * xi * xi + dk * xio);
            const float denom = sr + (dk + dk1 - 2.0f * sr) * xio;
            const float y = chk + __fdividef(numer, denom);
            const float dyd = __fdividef(sr * sr * (dk1 * xi * xi + 2.0f * sr * xio + dk * om * om),
                                         denom * denom);
            // fold 3 logs into 1: log(a)+log(b)-log(c) = log(a*b/c); clamps kept
            const float lg = __logf(__fdividef(fmaxf(dyd, 1e-10f) * fmaxf(hk, 1e-10f),
                                               fmaxf(wk, 1e-10f)));
            x  = inside ? y : x;
            ld += inside ? lg : 0.0f;
        }
    }
#undef STAGE
#undef PIECE8
#undef PIECE5
#undef INITACC
#undef CW
#undef ASPLIT
#undef BAR

    if (lane < 16) {
        const int gid = blk * MBLK + wave * 16 + lane;
        if (gid < B) {
            const float s = fmaxf(sclp[0], 0.1f);
            out[gid]     = fmaf(x, s, locp[0]);
            out[B + gid] = ld;
        }
    }
}

// ===========================================================================
// Fallback (proven round-2 fp32 kernel) if ws is too small for weight prep
// ===========================================================================
#define FBLK 256
template<int KIN, int WS, int NOUT, bool ACT>
__device__ __forceinline__ void dense_chunk(const float* __restrict__ W,
                                            const float* __restrict__ bias,
                                            int j0, const float (&hin)[KIN],
                                            float* __restrict__ sb, int tid)
{
    #pragma unroll 1
    for (int jj = 0; jj < NOUT; jj += 8) {
        const int j = j0 + jj;
        float a[8];
        #pragma unroll
        for (int u = 0; u < 8; ++u) a[u] = bias[j + u];
        #pragma unroll
        for (int k = 0; k < KIN; ++k) {
            const float* w = W + k * WS + j;
            const float hk = hin[k];
            #pragma unroll
            for (int u = 0; u < 8; ++u) a[u] = fmaf(hk, w[u], a[u]);
        }
        #pragma unroll
        for (int u = 0; u < 8; ++u) {
            float v = ACT ? silu_f(a[u]) : a[u];
            sb[(jj + u) * FBLK + tid] = v;
        }
    }
}

__global__ __launch_bounds__(FBLK, 2)
void nsf_fwd_slow(const float* __restrict__ z_g, const float* __restrict__ ctx_g,
                  const float* __restrict__ W0g, const float* __restrict__ b0g,
                  const float* __restrict__ W1g, const float* __restrict__ b1g,
                  const float* __restrict__ W2g, const float* __restrict__ b2g,
                  const float* __restrict__ W3g, const float* __restrict__ b3g,
                  const float* __restrict__ locp, const float* __restrict__ sclp,
                  float* __restrict__ out, int B)
{
    __shared__ float sbuf[64 * FBLK];
    const int tid = threadIdx.x;
    const int gid = blockIdx.x * FBLK + tid;
    if (gid >= B) return;
    float x = z_g[gid], ld = 0.0f;
    #pragma unroll 1
    for (int t = 0; t < TSTEPS; ++t) {
        asm volatile("" ::: "memory");
        const float* W0 = W0g + (size_t)t * DCOND * HID;
        const float* b0 = b0g + (size_t)t * HID;
        const float* W1 = W1g + (size_t)t * HID * HID;
        const float* b1 = b1g + (size_t)t * HID;
        const float* W2 = W2g + (size_t)t * HID * HID;
        const float* b2 = b2g + (size_t)t * HID;
        const float* W3 = W3g + (size_t)t * HID * NPAR;
        const float* b3 = b3g + (size_t)t * NPAR;
        float ctx[DCOND];
        #pragma unroll
        for (int k = 0; k < DCOND; ++k) ctx[k] = ctx_g[(size_t)gid * DCOND + k];
        float h[HID];
        dense_chunk<DCOND, HID, 64, true>(W0, b0, 0, ctx, sbuf, tid);
        #pragma unroll
        for (int j = 0; j < 64; ++j) h[j] = sbuf[j * FBLK + tid];
        dense_chunk<DCOND, HID, 64, true>(W0, b0, 64, ctx, sbuf, tid);
        #pragma unroll
        for (int j = 0; j < 64; ++j) h[64 + j] = sbuf[j * FBLK + tid];
        #pragma unroll 1
        for (int l = 0; l < 2; ++l) {
            const float* W  = (l == 0) ? W1 : W2;
            const float* bb = (l == 0) ? b1 : b2;
            float hlo[64];
            dense_chunk<HID, HID, 64, true>(W, bb, 0, h, sbuf, tid);
            #pragma unroll
            for (int j = 0; j < 64; ++j) hlo[j] = sbuf[j * FBLK + tid];
            dense_chunk<HID, HID, 64, true>(W, bb, 64, h, sbuf, tid);
            #pragma unroll
            for (int j = 0; j < 64; ++j) h[64 + j] = sbuf[j * FBLK + tid];
            #pragma unroll
            for (int j = 0; j < 64; ++j) h[j] = hlo[j];
        }
        float p[NPAR];
        dense_chunk<HID, NPAR, 64, false>(W3, b3, 0, h, sbuf, tid);
        #pragma unroll
        for (int j = 0; j < 64; ++j) p[j] = sbuf[j * FBLK + tid];
        dense_chunk<HID, NPAR, 8, false>(W3, b3, 64, h, sbuf, tid);
        #pragma unroll
        for (int j = 0; j < 8; ++j) p[64 + j] = sbuf[j * FBLK + tid];
        {
            float a = b3[72];
            #pragma unroll
            for (int k = 0; k < HID; ++k) a = fmaf(h[k], W3[k * NPAR + 72], a);
            p[72] = a;
        }
        float mw = p[0];
        #pragma unroll
        for (int i = 1; i < KBINS; ++i) mw = fmaxf(mw, p[i]);
        float we[KBINS]; float wsum = 0.0f;
        #pragma unroll
        for (int i = 0; i < KBINS; ++i) { we[i] = __expf(p[i] - mw); wsum += we[i]; }
        const float wmul = __fdividef(2.0f * TAILF, wsum);
        float mh = p[KBINS];
        #pragma unroll
        for (int i = 1; i < KBINS; ++i) mh = fmaxf(mh, p[KBINS + i]);
        float he[KBINS]; float hsum = 0.0f;
        #pragma unroll
        for (int i = 0; i < KBINS; ++i) { he[i] = __expf(p[KBINS + i] - mh); hsum += he[i]; }
        const float hmul = __fdividef(2.0f * TAILF, hsum);
        float dvv[KBINS + 1];
        #pragma unroll
        for (int i = 0; i <= KBINS; ++i) {
            float xd = p[2 * KBINS + i];
            dvv[i] = fmaxf(xd, 0.0f) + __logf(1.0f + __expf(-fabsf(xd))) + 0.001f;
        }
        float cw = 0.0f, ch = 0.0f, cwk = -TAILF, chk = -TAILF;
        float wk = we[0] * wmul, hk = he[0] * hmul, dk = dvv[0], dk1 = dvv[1];
        #pragma unroll
        for (int i = 1; i < KBINS; ++i) {
            cw += we[i - 1] * wmul;
            ch += he[i - 1] * hmul;
            if (cw < x) {
                cwk = cw; chk = ch;
                wk = we[i] * wmul; hk = he[i] * hmul;
                dk = dvv[i]; dk1 = dvv[i + 1];
            }
        }
        const bool inside = (x >= -TAILF) && (x <= TAILF);
        const float sr = __fdividef(hk, wk);
        float xi = __fdividef(x - cwk, wk);
        xi = fminf(fmaxf(xi, 1e-6f), 1.0f - 1e-6f);
        const float om  = 1.0f - xi;
        const float xio = xi * om;
        const float numer = hk * (sr * xi * xi + dk * xio);
        const float denom = sr + (dk + dk1 - 2.0f * sr) * xio;
        const float y = chk + __fdividef(numer, denom);
        const float dyd = __fdividef(sr * sr * (dk1 * xi * xi + 2.0f * sr * xio + dk * om * om),
                                     denom * denom);
        const float lg = __logf(fmaxf(dyd, 1e-10f)) + __logf(fmaxf(hk, 1e-10f))
                       - __logf(fmaxf(wk, 1e-10f));
        x  = inside ? y : x;
        ld += inside ? lg : 0.0f;
    }
    const float s = fmaxf(sclp[0], 0.1f);
    out[gid]     = fmaf(x, s, locp[0]);
    out[B + gid] = ld;
}

// ===========================================================================
extern "C" void kernel_launch(void* const* d_in, const int* in_sizes, int n_in,
                              void* d_out, int out_size, void* d_ws, size_t ws_size,
                              hipStream_t stream) {
    const float* z    = (const float*)d_in[0];
    const float* ctx  = (const float*)d_in[1];
    const float* W0   = (const float*)d_in[2];
    const float* b0   = (const float*)d_in[3];
    const float* W1   = (const float*)d_in[4];
    const float* b1   = (const float*)d_in[5];
    const float* W2   = (const float*)d_in[6];
    const float* b2   = (const float*)d_in[7];
    const float* W3   = (const float*)d_in[8];
    const float* b3   = (const float*)d_in[9];
    const float* loc  = (const float*)d_in[10];
    const float* scl  = (const float*)d_in[11];
    float* out = (float*)d_out;
    const int B = in_sizes[0];

    const size_t ws_need = (size_t)TSTEPS * 102400 * sizeof(short);   // 2,048,000 B
    if (ws_size < ws_need) {
        const int nblk = (B + FBLK - 1) / FBLK;
        hipLaunchKernelGGL(nsf_fwd_slow, dim3(nblk), dim3(FBLK), 0, stream,
                           z, ctx, W0, b0, W1, b1, W2, b2, W3, b3, loc, scl, out, B);
        return;
    }

    short* ws = (short*)d_ws;
    const int prep_total = TSTEPS * 102400;
    hipLaunchKernelGGL(prep_w, dim3((prep_total + 255) / 256), dim3(256), 0, stream,
                       W0, W1, W2, W3, ws);

    const int nblk = (B + MBLK - 1) / MBLK;   // 2048 blocks
    hipLaunchKernelGGL(nsf_mfma, dim3(nblk), dim3(NTHR), 0, stream,
                       z, ctx, b0, b1, b2, b3, loc, scl, ws, out, B);
}